// Round 3
// baseline (684.519 us; speedup 1.0000x reference)
//
#include <hip/hip_runtime.h>
#include <hip/hip_bf16.h>
#include <stdint.h>

// Problem constants
#define LNUM   2
#define F0     64
#define F1     32
#define NBASIS 8
#define WH     64     // radial MLP hidden width
#define RWN    192    // 2*F0 + 2*F1
#define NINVD  64
#define NVECD  16
#define BB     4
#define NN     512

// Tuning constants
#define TROWS  2048        // table rows over d in [0,8); rw(d>6) ~ 0 exactly (no bias)
#define TPAD   256         // padded row width (bf16 cols) = 512 B; slice w at col w*32 (64B line)
#define TSCALE 256.0f      // rows per unit d
#define NF     384         // per-node row: hm(64)|hsv(32)|hvv(96)|hv0(192)
#define SSPLIT 16          // sender splits
#define CHUNK  32          // NN / SSPLIT senders per block
#define ACC    160         // 64 (a0) + 96 (a1) accumulated features
#define RTILES 8           // receiver tiles of 64 per batch
#define INV_OFF (BB * NN * NVECD * 3)   // 98304: vecf comes first in d_out

typedef float f32x4 __attribute__((ext_vector_type(4)));

__device__ __forceinline__ uint32_t f2bf(float f) {   // RTN-even bf16 bits
  uint32_t b = __float_as_uint(f);
  return (b + 0x7fffu + ((b >> 16) & 1u)) >> 16;
}

// ---------------------------------------------------------------------------
// Radial table: rw(d) = silu(rb(d) @ Wr1) @ Wr2, bf16, rows padded to 512 B.
// Slice w (wave w's 24 values [w0(8)|w3(8)|w1(4)|w2(4)]) lives at col w*32:
// one 64B line per (row, wave). Row TROWS is all zeros (masked diagonal).
// 256 threads: t = w*32 + o.
// ---------------------------------------------------------------------------
__global__ void table_k(const float* __restrict__ Wr1, const float* __restrict__ Wr2,
                        __hip_bfloat16* __restrict__ table) {
  int row = blockIdx.x;                  // 0 .. LNUM*(TROWS+1)-1
  int l   = row / (TROWS + 1);
  int j   = row - l * (TROWS + 1);
  int t   = threadIdx.x;                 // 0..255
  __shared__ float h[WH];
  if (j == TROWS) {
    table[(size_t)row * TPAD + t] = __float2bfloat16(0.0f);
    return;
  }
  float d = (float)j * (1.0f / TSCALE);
  if (t < WH) {
    float acc = 0.0f;
#pragma unroll
    for (int b = 0; b < NBASIS; b++) {
      float dd = d - (4.0f / 7.0f) * (float)b;   // centers = linspace(0,4,8)
      acc += __expf(-4.0f * dd * dd) * Wr1[(l * NBASIS + b) * WH + t];
    }
    h[t] = acc / (1.0f + __expf(-acc));          // silu
  }
  __syncthreads();
  int w = t >> 5, o = t & 31;
  float a = 0.0f;
  if (o < 24) {
    int col;
    if      (o < 8)  col = 8 * w + o;              // w0
    else if (o < 16) col = 64 + 8 * w + (o - 8);   // w3
    else if (o < 20) col = 128 + 4 * w + (o - 16); // w1
    else             col = 160 + 4 * w + (o - 20); // w2
    for (int k = 0; k < WH; k++) a += h[k] * Wr2[(l * WH + k) * RWN + col];
  }
  table[(size_t)row * TPAD + t] = __float2bfloat16(a);
}

// ---------------------------------------------------------------------------
// Edge geometry, layer-independent: per edge (s,r) pack
// (bf16 u0, bf16 u1 | bf16 u2, u16 j) into uint2.  j==TROWS for diagonal.
// grid = BB*64 blocks (sender groups of 8), 512 threads = 8 waves.
// ---------------------------------------------------------------------------
__global__ void geom_k(const float* __restrict__ x, uint2* __restrict__ geom) {
  int blk = blockIdx.x;
  int b   = blk >> 6;          // batch
  int sg  = blk & 63;          // sender group
  int tid  = threadIdx.x;
  int w    = tid >> 6;
  int lane = tid & 63;
  int s    = sg * 8 + w;
  __shared__ float xs[NN * 3];
  for (int i = tid; i < NN * 3; i += 512) xs[i] = x[(size_t)b * NN * 3 + i];
  __syncthreads();
  float xs0 = xs[s * 3], xs1 = xs[s * 3 + 1], xs2 = xs[s * 3 + 2];
  for (int r = lane; r < NN; r += 64) {
    float v0 = xs[r * 3] - xs0, v1 = xs[r * 3 + 1] - xs1, v2 = xs[r * 3 + 2] - xs2;
    float d = sqrtf(v0 * v0 + v1 * v1 + v2 * v2);
    float inv = 1.0f / (d + 1e-8f);
    float u0 = v0 * inv, u1 = v1 * inv, u2 = v2 * inv;
    uint32_t j = (uint32_t)fminf(d * TSCALE + 0.5f, (float)(TROWS - 1));
    if (r == s) j = TROWS;
    uint2 g;
    g.x = f2bf(u0) | (f2bf(u1) << 16);
    g.y = f2bf(u2) | (j << 16);
    geom[((size_t)b * NN + s) * NN + r] = g;
  }
}

// h_s = broadcast embed row; h_v = 0
__global__ void init_k(const float* __restrict__ embed,
                       float* __restrict__ h_s, float* __restrict__ h_v) {
  int i = blockIdx.x * 256 + threadIdx.x;
  if (i < BB * NN * F0) h_s[i] = embed[i % F0];
  if (i < BB * NN * F1 * 3) h_v[i] = 0.0f;
}

// ---------------------------------------------------------------------------
// Per-node precompute for layer l (weights pre-offset by caller):
// nf[node] = [ hm = h_s@Wm (64) | hsv = h_s@Wsv (32) | hvv[c][i] (96) | hv0[i][f] (192) ]
// ---------------------------------------------------------------------------
__global__ void nodeprep_k(const float* __restrict__ h_s, const float* __restrict__ h_v,
                           const float* __restrict__ Wm, const float* __restrict__ Wsv,
                           const float* __restrict__ Wvv, const float* __restrict__ Wv0,
                           float* __restrict__ nf) {
  int node = blockIdx.x;      // 0 .. BB*NN-1
  int lane = threadIdx.x;     // 64
  __shared__ float hs[F0];
  __shared__ float hv[F1 * 3];
  hs[lane] = h_s[(size_t)node * F0 + lane];
  hv[lane] = h_v[(size_t)node * F1 * 3 + lane];
  if (lane < 32) hv[64 + lane] = h_v[(size_t)node * F1 * 3 + 64 + lane];
  __syncthreads();
  float* out = nf + (size_t)node * NF;
  {  // hm
    float a = 0.0f;
    for (int k = 0; k < F0; k++) a += hs[k] * Wm[k * F0 + lane];
    out[lane] = a;
  }
  if (lane < F1) {  // hsv
    float a = 0.0f;
    for (int k = 0; k < F0; k++) a += hs[k] * Wsv[k * F1 + lane];
    out[64 + lane] = a;
  }
  for (int o = lane; o < 96; o += 64) {  // hvv[c][i] = sum_f h_v[f][i] * Wvv[f][c]
    int c = o / 3, i = o - c * 3;
    float a = 0.0f;
    for (int f = 0; f < F1; f++) a += hv[f * 3 + i] * Wvv[f * F1 + c];
    out[96 + o] = a;
  }
  for (int o = lane; o < 192; o += 64) {  // hv0[i][f] = sum_c h_v[c][i] * Wv0[c][f]
    int i = o >> 6, f = o & 63;
    float a = 0.0f;
    for (int c = 0; c < F1; c++) a += hv[c * 3 + i] * Wv0[c * F0 + f];
    out[192 + o] = a;
  }
}

// ---------------------------------------------------------------------------
// Message + scatter. Block = (batch, 64-receiver tile, 32-sender chunk),
// 512 threads = 8 waves = 8 feature slices; lane = receiver.
// Sender features broadcast from LDS (b128); edge geometry from 16 KB LDS
// slab; radial weights gathered from bf16 table (1 line/lane/iter),
// 2x-unrolled ping-pong pipeline, gathers issued 2 iters ahead.
// Writes deterministic partial sums: partial[b][ss][feat(160)][n].
// ---------------------------------------------------------------------------
__launch_bounds__(512, 4)
__global__ void msg_k(const float* __restrict__ nf, const __hip_bfloat16* __restrict__ table_l,
                      const uint2* __restrict__ geom, float* __restrict__ partial) {
  __shared__ float snf[CHUNK][NF];     // 48 KB
  __shared__ uint2 gs[CHUNK][64];      // 16 KB
  int bid = blockIdx.x;
  int b   = bid / (RTILES * SSPLIT);
  int rem = bid - b * (RTILES * SSPLIT);
  int rt  = rem / SSPLIT;
  int ss  = rem - rt * SSPLIT;
  int tid  = threadIdx.x;
  int w    = tid >> 6;     // feature slice 0..7
  int lane = tid & 63;     // local receiver
  int r    = rt * 64 + lane;

  const f32x4* src = (const f32x4*)(nf + (size_t)(b * NN + ss * CHUNK) * NF);
  for (int i = tid; i < CHUNK * NF / 4; i += 512) ((f32x4*)snf)[i] = src[i];
  const uint2* gsrc = geom + ((size_t)b * NN + ss * CHUNK) * NN + rt * 64;
  for (int i = tid; i < CHUNK * 64; i += 512)
    gs[i >> 6][i & 63] = gsrc[(size_t)(i >> 6) * NN + (i & 63)];
  __syncthreads();

  float a0[8];
  float a1[4][3];
#pragma unroll
  for (int k = 0; k < 8; k++) a0[k] = 0.0f;
#pragma unroll
  for (int c = 0; c < 4; c++) { a1[c][0] = 0.0f; a1[c][1] = 0.0f; a1[c][2] = 0.0f; }

  const uint32_t* tw = (const uint32_t*)table_l + w * 16;   // this wave's 64B slice

  auto fetch = [&](uint2 g, uint4& q0, uint4& q1, uint4& q2) {
    uint32_t j = g.y >> 16;
    const uint4* tp = (const uint4*)(tw + (size_t)j * (TPAD / 2));
    q0 = tp[0]; q1 = tp[1]; q2 = tp[2];          // 48B, single 64B line
  };

  auto compute = [&](int i, uint2 g, uint4 q0, uint4 q1, uint4 q2) {
    float cu0 = __uint_as_float(g.x << 16);
    float cu1 = __uint_as_float(g.x & 0xffff0000u);
    float cu2 = __uint_as_float(g.y << 16);
    uint32_t dw[12];
    ((uint4*)dw)[0] = q0; ((uint4*)dw)[1] = q1; ((uint4*)dw)[2] = q2;
    float wv[24];   // [w0(8)|w3(8)|w1(4)|w2(4)]
#pragma unroll
    for (int m = 0; m < 12; m++) {
      wv[2 * m]     = __uint_as_float(dw[m] << 16);
      wv[2 * m + 1] = __uint_as_float(dw[m] & 0xffff0000u);
    }
    const float* sn = &snf[i][0];
    // a0: w0*hm + w3*(u . hv0)  -- all LDS reads are b128 broadcasts
    f32x4 hmA = *(const f32x4*)(sn + w * 8);
    f32x4 hmB = *(const f32x4*)(sn + w * 8 + 4);
    f32x4 p0A = *(const f32x4*)(sn + 192 + w * 8);
    f32x4 p0B = *(const f32x4*)(sn + 192 + w * 8 + 4);
    f32x4 p1A = *(const f32x4*)(sn + 256 + w * 8);
    f32x4 p1B = *(const f32x4*)(sn + 256 + w * 8 + 4);
    f32x4 p2A = *(const f32x4*)(sn + 320 + w * 8);
    f32x4 p2B = *(const f32x4*)(sn + 320 + w * 8 + 4);
#pragma unroll
    for (int k = 0; k < 4; k++) {
      float dvA = cu0 * p0A[k] + cu1 * p1A[k] + cu2 * p2A[k];
      a0[k]     += wv[k] * hmA[k] + wv[8 + k] * dvA;
      float dvB = cu0 * p0B[k] + cu1 * p1B[k] + cu2 * p2B[k];
      a0[4 + k] += wv[4 + k] * hmB[k] + wv[12 + k] * dvB;
    }
    // a1: (w1*hsv + w2*(u.hvv))*u - (w2/3)*hvv
    f32x4 hsv4 = *(const f32x4*)(sn + 64 + w * 4);
    float ga[12];
    *(f32x4*)&ga[0] = *(const f32x4*)(sn + 96 + w * 12);
    *(f32x4*)&ga[4] = *(const f32x4*)(sn + 96 + w * 12 + 4);
    *(f32x4*)&ga[8] = *(const f32x4*)(sn + 96 + w * 12 + 8);
#pragma unroll
    for (int c = 0; c < 4; c++) {
      float g0 = ga[c * 3 + 0], g1 = ga[c * 3 + 1], g2 = ga[c * 3 + 2];
      float qd = cu0 * g0 + cu1 * g1 + cu2 * g2;
      float coef = wv[16 + c] * hsv4[c] + wv[20 + c] * qd;
      float t3 = wv[20 + c] * (1.0f / 3.0f);
      a1[c][0] += coef * cu0 - t3 * g0;
      a1[c][1] += coef * cu1 - t3 * g1;
      a1[c][2] += coef * cu2 - t3 * g2;
    }
  };

  uint2 gcur = gs[0][lane];
  uint2 gnx  = gs[1][lane];
  uint4 qa0, qa1, qa2, qb0, qb1, qb2;
  fetch(gcur, qa0, qa1, qa2);
  fetch(gnx,  qb0, qb1, qb2);

  for (int i = 0; i < CHUNK; i += 2) {
    uint2 g2 = (i + 2 < CHUNK) ? gs[i + 2][lane] : make_uint2(0, 0);
    compute(i, gcur, qa0, qa1, qa2);
    if (i + 2 < CHUNK) fetch(g2, qa0, qa1, qa2);
    uint2 g3 = (i + 3 < CHUNK) ? gs[i + 3][lane] : make_uint2(0, 0);
    compute(i + 1, gnx, qb0, qb1, qb2);
    if (i + 3 < CHUNK) fetch(g3, qb0, qb1, qb2);
    gcur = g2; gnx = g3;
  }

  float* pw = partial + (size_t)(b * SSPLIT + ss) * ACC * NN;
#pragma unroll
  for (int k = 0; k < 8; k++) pw[(w * 8 + k) * NN + r] = a0[k];
#pragma unroll
  for (int c = 0; c < 4; c++) {
    int ch = w * 4 + c;
#pragma unroll
    for (int i = 0; i < 3; i++) pw[(64 + ch * 3 + i) * NN + r] = a1[c][i];
  }
}

// ---------------------------------------------------------------------------
// Reduce partials, polynomial correction, node update (weights pre-offset).
// ---------------------------------------------------------------------------
__global__ void update_k(const float* __restrict__ partial, const float* __restrict__ Wc,
                         const float* __restrict__ Wself,
                         float* __restrict__ h_s, float* __restrict__ h_v) {
  int node = blockIdx.x;
  int b = node >> 9, n = node & 511;
  int lane = threadIdx.x;   // 64
  __shared__ float a0s[F0], a2s[F0], a3s[F0], hss[F0];
  const float invn = 1.0f / (float)NN;
  float a = 0.0f;
  for (int ss = 0; ss < SSPLIT; ss++)
    a += partial[((size_t)(b * SSPLIT + ss) * ACC + lane) * NN + n];
  a *= invn;
  a0s[lane] = a; a2s[lane] = a * a; a3s[lane] = a * a * a;
  hss[lane] = h_s[(size_t)node * F0 + lane];
  for (int o = lane; o < 96; o += 64) {
    float v = 0.0f;
    for (int ss = 0; ss < SSPLIT; ss++)
      v += partial[((size_t)(b * SSPLIT + ss) * ACC + 64 + o) * NN + n];
    h_v[(size_t)node * F1 * 3 + o] += v * invn;
  }
  __syncthreads();
  float val = 0.0f;
  for (int f = 0; f < F0; f++) {
    val += hss[f] * Wself[f * F0 + lane];
    val += a0s[f] * Wc[(0 * F0 + f) * F0 + lane];
    val += a2s[f] * Wc[(1 * F0 + f) * F0 + lane];
    val += a3s[f] * Wc[(2 * F0 + f) * F0 + lane];
  }
  h_s[(size_t)node * F0 + lane] = val;
}

// Output head: vecf = h_v @ Woutv (first), inv = silu(h_s)@Wouts@Wfin + bfin.
__global__ void out_k(const float* __restrict__ h_s, const float* __restrict__ h_v,
                      const float* __restrict__ Wouts, const float* __restrict__ Wfin,
                      const float* __restrict__ bfin, const float* __restrict__ Woutv,
                      float* __restrict__ out) {
  int node = blockIdx.x;
  int lane = threadIdx.x;   // 64
  __shared__ float t[F0], g[NINVD];
  float h = h_s[(size_t)node * F0 + lane];
  t[lane] = h / (1.0f + __expf(-h));
  __syncthreads();
  float a = 0.0f;
  for (int f = 0; f < F0; f++) a += t[f] * Wouts[f * NINVD + lane];
  g[lane] = a;
  __syncthreads();
  float v = bfin[lane];
  for (int k = 0; k < NINVD; k++) v += g[k] * Wfin[k * NINVD + lane];
  out[INV_OFF + (size_t)node * NINVD + lane] = v;
  if (lane < NVECD * 3) {
    int gg = lane / 3, i = lane - gg * 3;
    float s = 0.0f;
    for (int f = 0; f < F1; f++) s += h_v[(size_t)node * F1 * 3 + f * 3 + i] * Woutv[f * NVECD + gg];
    out[(size_t)node * (NVECD * 3) + lane] = s;
  }
}

extern "C" void kernel_launch(void* const* d_in, const int* in_sizes, int n_in,
                              void* d_out, int out_size, void* d_ws, size_t ws_size,
                              hipStream_t stream) {
  const float* x     = (const float*)d_in[0];
  // d_in[1] senders, d_in[2] receivers: dense-graph structure is known, unused.
  const float* embed = (const float*)d_in[3];
  const float* Wr1   = (const float*)d_in[4];
  const float* Wr2   = (const float*)d_in[5];
  const float* Wm    = (const float*)d_in[6];
  const float* Wc    = (const float*)d_in[7];
  const float* Wself = (const float*)d_in[8];
  const float* Wsv   = (const float*)d_in[9];
  const float* Wvv   = (const float*)d_in[10];
  const float* Wv0   = (const float*)d_in[11];
  const float* Wouts = (const float*)d_in[12];
  const float* Woutv = (const float*)d_in[13];
  const float* Wfin  = (const float*)d_in[14];
  const float* bfin  = (const float*)d_in[15];
  float* out = (float*)d_out;

  char* ws = (char*)d_ws;
  size_t off = 0;
  auto wsalloc = [&](size_t bytes) {
    void* p = ws + off;
    off += (bytes + 255) & ~(size_t)255;
    return p;
  };
  __hip_bfloat16* table = (__hip_bfloat16*)wsalloc((size_t)LNUM * (TROWS + 1) * TPAD * 2);
  uint2* geomp   = (uint2*)wsalloc((size_t)BB * NN * NN * 8);
  float* h_s     = (float*)wsalloc((size_t)BB * NN * F0 * 4);
  float* h_v     = (float*)wsalloc((size_t)BB * NN * F1 * 3 * 4);
  float* nf      = (float*)wsalloc((size_t)BB * NN * NF * 4);
  float* partial = (float*)wsalloc((size_t)BB * SSPLIT * ACC * NN * 4);
  // total workspace: ~37 MB

  table_k<<<LNUM * (TROWS + 1), 256, 0, stream>>>(Wr1, Wr2, table);
  geom_k<<<BB * 64, 512, 0, stream>>>(x, geomp);
  init_k<<<(BB * NN * F1 * 3 + 255) / 256, 256, 0, stream>>>(embed, h_s, h_v);
  for (int l = 0; l < LNUM; l++) {
    nodeprep_k<<<BB * NN, 64, 0, stream>>>(h_s, h_v,
                                           Wm + l * F0 * F0, Wsv + l * F0 * F1,
                                           Wvv + l * F1 * F1, Wv0 + l * F1 * F0, nf);
    msg_k<<<BB * RTILES * SSPLIT, 512, 0, stream>>>(nf, table + (size_t)l * (TROWS + 1) * TPAD,
                                                    geomp, partial);
    update_k<<<BB * NN, 64, 0, stream>>>(partial, Wc + l * 3 * F0 * F0,
                                         Wself + l * F0 * F0, h_s, h_v);
  }
  out_k<<<BB * NN, 64, 0, stream>>>(h_s, h_v, Wouts, Wfin, bfin, Woutv, out);
}

// Round 4
// 522.092 us; speedup vs baseline: 1.3111x; 1.3111x over previous
//
#include <hip/hip_runtime.h>
#include <hip/hip_bf16.h>
#include <stdint.h>

// Problem constants
#define LNUM   2
#define F0     64
#define F1     32
#define NBASIS 8
#define WH     64     // radial MLP hidden width
#define RWN    192    // 2*F0 + 2*F1
#define NINVD  64
#define NVECD  16
#define BB     4
#define NN     512

// Tuning constants
#define TROWS  2048        // table rows over d in [0,8)
#define TPAD   256         // padded row width (bf16) = 512 B; slice w at col w*32 (one 64B line)
#define TSCALE 256.0f      // rows per unit d
#define NF     388         // per-node row: hm(64)|hsv(32)|hvv(96)|hv0(192)|x(3)|pad(1)
#define SSPLIT 32          // sender splits
#define CHUNK  16          // NN / SSPLIT senders per block
#define ACC    160         // 64 (a0) + 96 (a1) accumulated features
#define INV_OFF (BB * NN * NVECD * 3)   // vecf comes first in d_out

typedef float f32x4 __attribute__((ext_vector_type(4)));

// bf16 element e from packed u32 array (static e only!)
#define BF(arr, e) (((e) & 1) ? __uint_as_float((arr)[(e) >> 1] & 0xffff0000u) \
                              : __uint_as_float((arr)[(e) >> 1] << 16))

// ---------------------------------------------------------------------------
// Radial table: rw(d) = silu(rb(d) @ Wr1) @ Wr2, bf16, rows padded to 512 B.
// Slice w = 24 values [w0(8)|w3(8)|w1(4)|w2(4)] at col w*32 (one 64B line).
// Row TROWS is all zeros (masked diagonal). 256 threads: t = w*32 + o.
// ---------------------------------------------------------------------------
__global__ void table_k(const float* __restrict__ Wr1, const float* __restrict__ Wr2,
                        __hip_bfloat16* __restrict__ table) {
  int row = blockIdx.x;                  // 0 .. LNUM*(TROWS+1)-1
  int l   = row / (TROWS + 1);
  int j   = row - l * (TROWS + 1);
  int t   = threadIdx.x;                 // 0..255
  __shared__ float h[WH];
  if (j == TROWS) {
    table[(size_t)row * TPAD + t] = __float2bfloat16(0.0f);
    return;
  }
  float d = (float)j * (1.0f / TSCALE);
  if (t < WH) {
    float acc = 0.0f;
#pragma unroll
    for (int b = 0; b < NBASIS; b++) {
      float dd = d - (4.0f / 7.0f) * (float)b;   // centers = linspace(0,4,8)
      acc += __expf(-4.0f * dd * dd) * Wr1[(l * NBASIS + b) * WH + t];
    }
    h[t] = acc / (1.0f + __expf(-acc));          // silu
  }
  __syncthreads();
  int w = t >> 5, o = t & 31;
  float a = 0.0f;
  if (o < 24) {
    int col;
    if      (o < 8)  col = 8 * w + o;              // w0
    else if (o < 16) col = 64 + 8 * w + (o - 8);   // w3
    else if (o < 20) col = 128 + 4 * w + (o - 16); // w1
    else             col = 160 + 4 * w + (o - 20); // w2
    for (int k = 0; k < WH; k++) a += h[k] * Wr2[(l * WH + k) * RWN + col];
  }
  table[(size_t)row * TPAD + t] = __float2bfloat16(a);
}

// h_s = broadcast embed row; h_v = 0
__global__ void init_k(const float* __restrict__ embed,
                       float* __restrict__ h_s, float* __restrict__ h_v) {
  int i = blockIdx.x * 256 + threadIdx.x;
  if (i < BB * NN * F0) h_s[i] = embed[i % F0];
  if (i < BB * NN * F1 * 3) h_v[i] = 0.0f;
}

// ---------------------------------------------------------------------------
// Per-node precompute for layer l (weights pre-offset by caller):
// nf[node] = [ hm (64) | hsv (32) | hvv[c][i] (96) | hv0[i][f] (192) | x (3) | pad ]
// ---------------------------------------------------------------------------
__global__ void nodeprep_k(const float* __restrict__ h_s, const float* __restrict__ h_v,
                           const float* __restrict__ x,
                           const float* __restrict__ Wm, const float* __restrict__ Wsv,
                           const float* __restrict__ Wvv, const float* __restrict__ Wv0,
                           float* __restrict__ nf) {
  int node = blockIdx.x;      // 0 .. BB*NN-1
  int lane = threadIdx.x;     // 64
  __shared__ float hs[F0];
  __shared__ float hv[F1 * 3];
  hs[lane] = h_s[(size_t)node * F0 + lane];
  hv[lane] = h_v[(size_t)node * F1 * 3 + lane];
  if (lane < 32) hv[64 + lane] = h_v[(size_t)node * F1 * 3 + 64 + lane];
  __syncthreads();
  float* out = nf + (size_t)node * NF;
  {  // hm
    float a = 0.0f;
    for (int k = 0; k < F0; k++) a += hs[k] * Wm[k * F0 + lane];
    out[lane] = a;
  }
  if (lane < F1) {  // hsv
    float a = 0.0f;
    for (int k = 0; k < F0; k++) a += hs[k] * Wsv[k * F1 + lane];
    out[64 + lane] = a;
  }
  for (int o = lane; o < 96; o += 64) {  // hvv[c][i] = sum_f h_v[f][i] * Wvv[f][c]
    int c = o / 3, i = o - c * 3;
    float a = 0.0f;
    for (int f = 0; f < F1; f++) a += hv[f * 3 + i] * Wvv[f * F1 + c];
    out[96 + o] = a;
  }
  for (int o = lane; o < 192; o += 64) {  // hv0[i][f] = sum_c h_v[c][i] * Wv0[c][f]
    int i = o >> 6, f = o & 63;
    float a = 0.0f;
    for (int c = 0; c < F1; c++) a += hv[c * 3 + i] * Wv0[c * F0 + f];
    out[192 + o] = a;
  }
  if (lane < 3) out[384 + lane] = x[(size_t)node * 3 + lane];
  if (lane == 3) out[387] = 0.0f;
}

// ---------------------------------------------------------------------------
// Message + scatter, RT2: block = (batch, 128-receiver pair-tile, 16-sender
// chunk), 512 threads = 8 waves = 8 feature slices; lane = receiver; each
// wave accumulates TWO receiver tiles (r0, r0+64) so every LDS broadcast
// feeds 128 edges. Geometry inline (rsqrt); radial weights gathered from
// padded bf16 table (one 64B line per row-slice).
// Straight-line code, static indexing only (R3 scratch-spill lesson).
// ---------------------------------------------------------------------------
__launch_bounds__(512, 4)
__global__ void msg_k(const float* __restrict__ nf, const __hip_bfloat16* __restrict__ table_l,
                      const float* __restrict__ x, float* __restrict__ partial) {
  __shared__ float snf[CHUNK][NF];     // 24.8 KB
  int bid = blockIdx.x;
  int b   = bid >> 7;          // /(4*SSPLIT)
  int rem = bid & 127;
  int rp  = rem >> 5;          // receiver pair-tile 0..3
  int ss  = rem & 31;          // sender chunk
  int tid  = threadIdx.x;
  int w    = tid >> 6;         // feature slice 0..7
  int lane = tid & 63;
  int r0   = rp * 128 + lane;  // tile0 receiver; tile1 = r0 + 64

  const f32x4* src = (const f32x4*)(nf + (size_t)(b * NN + ss * CHUNK) * NF);
  for (int i = tid; i < CHUNK * NF / 4; i += 512) ((f32x4*)snf)[i] = src[i];

  const float* xq = x + ((size_t)b * NN + r0) * 3;
  float xr00 = xq[0],   xr01 = xq[1],   xr02 = xq[2];
  float xr10 = xq[192], xr11 = xq[193], xr12 = xq[194];   // receiver r0+64
  __syncthreads();

  float a00[8], a01[8];        // a0 slices, tile0 / tile1
  float a10[12], a11[12];      // a1 slices (c*3+i), tile0 / tile1
#pragma unroll
  for (int k = 0; k < 8; k++) { a00[k] = 0.0f; a01[k] = 0.0f; }
#pragma unroll
  for (int k = 0; k < 12; k++) { a10[k] = 0.0f; a11[k] = 0.0f; }

  const uint32_t* tw = (const uint32_t*)table_l + w * 16;   // this wave's 64B column

  for (int i = 0; i < CHUNK; i++) {
    const float* sn = &snf[i][0];
    f32x4 xs = *(const f32x4*)(sn + 384);
    int sg = ss * CHUNK + i;
    // --- geometry tile0
    float v0 = xr00 - xs[0], v1 = xr01 - xs[1], v2 = xr02 - xs[2];
    float d2 = v0 * v0 + v1 * v1 + v2 * v2;
    float ri = rsqrtf(d2 + 1e-20f);
    int j0 = (int)fminf(d2 * ri * TSCALE + 0.5f, (float)(TROWS - 1));
    j0 = (sg == r0) ? TROWS : j0;
    float u00 = v0 * ri, u01 = v1 * ri, u02 = v2 * ri;
    // --- geometry tile1
    float y0 = xr10 - xs[0], y1 = xr11 - xs[1], y2 = xr12 - xs[2];
    float e2 = y0 * y0 + y1 * y1 + y2 * y2;
    float rj = rsqrtf(e2 + 1e-20f);
    int j1 = (int)fminf(e2 * rj * TSCALE + 0.5f, (float)(TROWS - 1));
    j1 = (sg == r0 + 64) ? TROWS : j1;
    float u10 = y0 * rj, u11 = y1 * rj, u12 = y2 * rj;
    // --- issue both gathers early (one 64B line each)
    const uint4* t0 = (const uint4*)(tw + (size_t)j0 * (TPAD / 2));
    const uint4* t1 = (const uint4*)(tw + (size_t)j1 * (TPAD / 2));
    uint4 qa0 = t0[0], qa1 = t0[1], qa2 = t0[2];
    uint4 qb0 = t1[0], qb1 = t1[1], qb2 = t1[2];
    // --- sender features (LDS broadcasts, b128)
    f32x4 hmA = *(const f32x4*)(sn + w * 8);
    f32x4 hmB = *(const f32x4*)(sn + w * 8 + 4);
    f32x4 p0A = *(const f32x4*)(sn + 192 + w * 8);
    f32x4 p0B = *(const f32x4*)(sn + 192 + w * 8 + 4);
    f32x4 p1A = *(const f32x4*)(sn + 256 + w * 8);
    f32x4 p1B = *(const f32x4*)(sn + 256 + w * 8 + 4);
    f32x4 p2A = *(const f32x4*)(sn + 320 + w * 8);
    f32x4 p2B = *(const f32x4*)(sn + 320 + w * 8 + 4);
    f32x4 hsv4 = *(const f32x4*)(sn + 64 + w * 4);
    float ga[12];
    *(f32x4*)(ga + 0) = *(const f32x4*)(sn + 96 + w * 12);
    *(f32x4*)(ga + 4) = *(const f32x4*)(sn + 96 + w * 12 + 4);
    *(f32x4*)(ga + 8) = *(const f32x4*)(sn + 96 + w * 12 + 8);

    // ---- tile0
    {
      uint32_t da[12];
      *(uint4*)(da + 0) = qa0; *(uint4*)(da + 4) = qa1; *(uint4*)(da + 8) = qa2;
#pragma unroll
      for (int k = 0; k < 4; k++) {
        float dvA = u00 * p0A[k] + u01 * p1A[k] + u02 * p2A[k];
        a00[k] += BF(da, k) * hmA[k] + BF(da, 8 + k) * dvA;
        float dvB = u00 * p0B[k] + u01 * p1B[k] + u02 * p2B[k];
        a00[4 + k] += BF(da, 4 + k) * hmB[k] + BF(da, 12 + k) * dvB;
      }
#pragma unroll
      for (int c = 0; c < 4; c++) {
        float g0 = ga[c * 3], g1 = ga[c * 3 + 1], g2 = ga[c * 3 + 2];
        float qd = u00 * g0 + u01 * g1 + u02 * g2;
        float w1c = BF(da, 16 + c);
        float w2c = BF(da, 20 + c);
        float coef = w1c * hsv4[c] + w2c * qd;
        float t3 = w2c * (1.0f / 3.0f);
        a10[c * 3]     += coef * u00 - t3 * g0;
        a10[c * 3 + 1] += coef * u01 - t3 * g1;
        a10[c * 3 + 2] += coef * u02 - t3 * g2;
      }
    }
    // ---- tile1 (reuses the same feature registers)
    {
      uint32_t db[12];
      *(uint4*)(db + 0) = qb0; *(uint4*)(db + 4) = qb1; *(uint4*)(db + 8) = qb2;
#pragma unroll
      for (int k = 0; k < 4; k++) {
        float dvA = u10 * p0A[k] + u11 * p1A[k] + u12 * p2A[k];
        a01[k] += BF(db, k) * hmA[k] + BF(db, 8 + k) * dvA;
        float dvB = u10 * p0B[k] + u11 * p1B[k] + u12 * p2B[k];
        a01[4 + k] += BF(db, 4 + k) * hmB[k] + BF(db, 12 + k) * dvB;
      }
#pragma unroll
      for (int c = 0; c < 4; c++) {
        float g0 = ga[c * 3], g1 = ga[c * 3 + 1], g2 = ga[c * 3 + 2];
        float qd = u10 * g0 + u11 * g1 + u12 * g2;
        float w1c = BF(db, 16 + c);
        float w2c = BF(db, 20 + c);
        float coef = w1c * hsv4[c] + w2c * qd;
        float t3 = w2c * (1.0f / 3.0f);
        a11[c * 3]     += coef * u10 - t3 * g0;
        a11[c * 3 + 1] += coef * u11 - t3 * g1;
        a11[c * 3 + 2] += coef * u12 - t3 * g2;
      }
    }
  }

  float* pw = partial + (size_t)(b * SSPLIT + ss) * ACC * NN;
#pragma unroll
  for (int k = 0; k < 8; k++) {
    pw[(w * 8 + k) * NN + r0]      = a00[k];
    pw[(w * 8 + k) * NN + r0 + 64] = a01[k];
  }
#pragma unroll
  for (int c = 0; c < 4; c++) {
#pragma unroll
    for (int i = 0; i < 3; i++) {
      pw[(64 + (w * 4 + c) * 3 + i) * NN + r0]      = a10[c * 3 + i];
      pw[(64 + (w * 4 + c) * 3 + i) * NN + r0 + 64] = a11[c * 3 + i];
    }
  }
}

// ---------------------------------------------------------------------------
// Reduce partials, polynomial correction, node update (weights pre-offset).
// ---------------------------------------------------------------------------
__global__ void update_k(const float* __restrict__ partial, const float* __restrict__ Wc,
                         const float* __restrict__ Wself,
                         float* __restrict__ h_s, float* __restrict__ h_v) {
  int node = blockIdx.x;
  int b = node >> 9, n = node & 511;
  int lane = threadIdx.x;   // 64
  __shared__ float a0s[F0], a2s[F0], a3s[F0], hss[F0];
  const float invn = 1.0f / (float)NN;
  float a = 0.0f;
  for (int ss = 0; ss < SSPLIT; ss++)
    a += partial[((size_t)(b * SSPLIT + ss) * ACC + lane) * NN + n];
  a *= invn;
  a0s[lane] = a; a2s[lane] = a * a; a3s[lane] = a * a * a;
  hss[lane] = h_s[(size_t)node * F0 + lane];
  for (int o = lane; o < 96; o += 64) {
    float v = 0.0f;
    for (int ss = 0; ss < SSPLIT; ss++)
      v += partial[((size_t)(b * SSPLIT + ss) * ACC + 64 + o) * NN + n];
    h_v[(size_t)node * F1 * 3 + o] += v * invn;
  }
  __syncthreads();
  float val = 0.0f;
  for (int f = 0; f < F0; f++) {
    val += hss[f] * Wself[f * F0 + lane];
    val += a0s[f] * Wc[(0 * F0 + f) * F0 + lane];
    val += a2s[f] * Wc[(1 * F0 + f) * F0 + lane];
    val += a3s[f] * Wc[(2 * F0 + f) * F0 + lane];
  }
  h_s[(size_t)node * F0 + lane] = val;
}

// Output head: vecf = h_v @ Woutv (first), inv = silu(h_s)@Wouts@Wfin + bfin.
__global__ void out_k(const float* __restrict__ h_s, const float* __restrict__ h_v,
                      const float* __restrict__ Wouts, const float* __restrict__ Wfin,
                      const float* __restrict__ bfin, const float* __restrict__ Woutv,
                      float* __restrict__ out) {
  int node = blockIdx.x;
  int lane = threadIdx.x;   // 64
  __shared__ float t[F0], g[NINVD];
  float h = h_s[(size_t)node * F0 + lane];
  t[lane] = h / (1.0f + __expf(-h));
  __syncthreads();
  float a = 0.0f;
  for (int f = 0; f < F0; f++) a += t[f] * Wouts[f * NINVD + lane];
  g[lane] = a;
  __syncthreads();
  float v = bfin[lane];
  for (int k = 0; k < NINVD; k++) v += g[k] * Wfin[k * NINVD + lane];
  out[INV_OFF + (size_t)node * NINVD + lane] = v;
  if (lane < NVECD * 3) {
    int gg = lane / 3, i = lane - gg * 3;
    float s = 0.0f;
    for (int f = 0; f < F1; f++) s += h_v[(size_t)node * F1 * 3 + f * 3 + i] * Woutv[f * NVECD + gg];
    out[(size_t)node * (NVECD * 3) + lane] = s;
  }
}

extern "C" void kernel_launch(void* const* d_in, const int* in_sizes, int n_in,
                              void* d_out, int out_size, void* d_ws, size_t ws_size,
                              hipStream_t stream) {
  const float* x     = (const float*)d_in[0];
  // d_in[1] senders, d_in[2] receivers: dense-graph structure is known, unused.
  const float* embed = (const float*)d_in[3];
  const float* Wr1   = (const float*)d_in[4];
  const float* Wr2   = (const float*)d_in[5];
  const float* Wm    = (const float*)d_in[6];
  const float* Wc    = (const float*)d_in[7];
  const float* Wself = (const float*)d_in[8];
  const float* Wsv   = (const float*)d_in[9];
  const float* Wvv   = (const float*)d_in[10];
  const float* Wv0   = (const float*)d_in[11];
  const float* Wouts = (const float*)d_in[12];
  const float* Woutv = (const float*)d_in[13];
  const float* Wfin  = (const float*)d_in[14];
  const float* bfin  = (const float*)d_in[15];
  float* out = (float*)d_out;

  char* ws = (char*)d_ws;
  size_t off = 0;
  auto wsalloc = [&](size_t bytes) {
    void* p = ws + off;
    off += (bytes + 255) & ~(size_t)255;
    return p;
  };
  __hip_bfloat16* table = (__hip_bfloat16*)wsalloc((size_t)LNUM * (TROWS + 1) * TPAD * 2);
  float* h_s     = (float*)wsalloc((size_t)BB * NN * F0 * 4);
  float* h_v     = (float*)wsalloc((size_t)BB * NN * F1 * 3 * 4);
  float* nf      = (float*)wsalloc((size_t)BB * NN * NF * 4);
  float* partial = (float*)wsalloc((size_t)BB * SSPLIT * ACC * NN * 4);
  // total workspace: ~48.5 MB

  table_k<<<LNUM * (TROWS + 1), 256, 0, stream>>>(Wr1, Wr2, table);
  init_k<<<(BB * NN * F1 * 3 + 255) / 256, 256, 0, stream>>>(embed, h_s, h_v);
  for (int l = 0; l < LNUM; l++) {
    nodeprep_k<<<BB * NN, 64, 0, stream>>>(h_s, h_v, x,
                                           Wm + l * F0 * F0, Wsv + l * F0 * F1,
                                           Wvv + l * F1 * F1, Wv0 + l * F1 * F0, nf);
    msg_k<<<BB * 4 * SSPLIT, 512, 0, stream>>>(nf, table + (size_t)l * (TROWS + 1) * TPAD,
                                               x, partial);
    update_k<<<BB * NN, 64, 0, stream>>>(partial, Wc + l * 3 * F0 * F0,
                                         Wself + l * F0 * F0, h_s, h_v);
  }
  out_k<<<BB * NN, 64, 0, stream>>>(h_s, h_v, Wouts, Wfin, bfin, Woutv, out);
}

// Round 5
// 212.213 us; speedup vs baseline: 3.2256x; 2.4602x over previous
//
#include <hip/hip_runtime.h>
#include <hip/hip_bf16.h>
#include <stdint.h>

// Problem constants
#define LNUM   2
#define F0     64
#define F1     32
#define NBASIS 8
#define WH     64     // radial MLP hidden width
#define RWN    192    // 2*F0 + 2*F1
#define NINVD  64
#define NVECD  16
#define BB     4
#define NN     512

// Tuning constants
#define TROWS  2048        // table rows over d in [0,8); rw(d>6) ~ 0 (no bias)
#define TSCALE 256.0f      // rows per unit d
#define NF     388         // per-node row: hm(64)|hsv(32)|hvv(96)|hv0(192)|x(3)|pad(1)
#define SSPLIT 16          // sender splits
#define CHUNK  32          // NN / SSPLIT senders per block
#define ACC    160         // 64 (a0) + 96 (a1) accumulated features
#define RTILES 8           // receiver tiles of 64 per batch
#define INV_OFF (BB * NN * NVECD * 3)   // vecf comes first in d_out

typedef float f32x4 __attribute__((ext_vector_type(4)));

// ---------------------------------------------------------------------------
// Radial table: rw(d) = silu(rb(d) @ Wr1) @ Wr2, stored bf16, columns permuted
// into 8 slices of 24 = [w0(8)|w3(8)|w1(4)|w2(4)]; row stride 384 B (6 lines).
// Row TROWS is all zeros (masked diagonal). 192 threads, one per column.
// ---------------------------------------------------------------------------
__global__ void table_k(const float* __restrict__ Wr1, const float* __restrict__ Wr2,
                        __hip_bfloat16* __restrict__ table) {
  int row = blockIdx.x;                  // 0 .. LNUM*(TROWS+1)-1
  int l   = row / (TROWS + 1);
  int j   = row - l * (TROWS + 1);
  int t   = threadIdx.x;                 // 0..191
  __shared__ float h[WH];
  if (j == TROWS) {                      // uniform per block
    table[(size_t)row * RWN + t] = __float2bfloat16(0.0f);
    return;
  }
  float d = (float)j * (1.0f / TSCALE);
  if (t < WH) {
    float acc = 0.0f;
#pragma unroll
    for (int b = 0; b < NBASIS; b++) {
      float dd = d - (4.0f / 7.0f) * (float)b;   // centers = linspace(0,4,8)
      acc += __expf(-4.0f * dd * dd) * Wr1[(l * NBASIS + b) * WH + t];
    }
    h[t] = acc / (1.0f + __expf(-acc));          // silu
  }
  __syncthreads();
  int w = t / 24, o = t - w * 24;
  int col;
  if      (o < 8)  col = 8 * w + o;              // w0 slice (cols 0..63)
  else if (o < 16) col = 64 + 8 * w + (o - 8);   // w3 slice (64..127)
  else if (o < 20) col = 128 + 4 * w + (o - 16); // w1 slice (128..159)
  else             col = 160 + 4 * w + (o - 20); // w2 slice (160..191)
  float a = 0.0f;
  for (int k = 0; k < WH; k++) a += h[k] * Wr2[(l * WH + k) * RWN + col];
  table[(size_t)row * RWN + t] = __float2bfloat16(a);
}

// h_s = broadcast embed row; h_v = 0
__global__ void init_k(const float* __restrict__ embed,
                       float* __restrict__ h_s, float* __restrict__ h_v) {
  int i = blockIdx.x * 256 + threadIdx.x;
  if (i < BB * NN * F0) h_s[i] = embed[i % F0];
  if (i < BB * NN * F1 * 3) h_v[i] = 0.0f;
}

// ---------------------------------------------------------------------------
// Per-node precompute for layer l (weights pre-offset by caller):
// nf[node] = [ hm (64) | hsv (32) | hvv[c][i] (96) | hv0[i][f] (192) | x (3) | pad ]
// ---------------------------------------------------------------------------
__global__ void nodeprep_k(const float* __restrict__ h_s, const float* __restrict__ h_v,
                           const float* __restrict__ x,
                           const float* __restrict__ Wm, const float* __restrict__ Wsv,
                           const float* __restrict__ Wvv, const float* __restrict__ Wv0,
                           float* __restrict__ nf) {
  int node = blockIdx.x;      // 0 .. BB*NN-1
  int lane = threadIdx.x;     // 64
  __shared__ float hs[F0];
  __shared__ float hv[F1 * 3];
  hs[lane] = h_s[(size_t)node * F0 + lane];
  hv[lane] = h_v[(size_t)node * F1 * 3 + lane];
  if (lane < 32) hv[64 + lane] = h_v[(size_t)node * F1 * 3 + 64 + lane];
  __syncthreads();
  float* out = nf + (size_t)node * NF;
  {  // hm
    float a = 0.0f;
    for (int k = 0; k < F0; k++) a += hs[k] * Wm[k * F0 + lane];
    out[lane] = a;
  }
  if (lane < F1) {  // hsv
    float a = 0.0f;
    for (int k = 0; k < F0; k++) a += hs[k] * Wsv[k * F1 + lane];
    out[64 + lane] = a;
  }
  for (int o = lane; o < 96; o += 64) {  // hvv[c][i] = sum_f h_v[f][i] * Wvv[f][c]
    int c = o / 3, i = o - c * 3;
    float a = 0.0f;
    for (int f = 0; f < F1; f++) a += hv[f * 3 + i] * Wvv[f * F1 + c];
    out[96 + o] = a;
  }
  for (int o = lane; o < 192; o += 64) {  // hv0[i][f] = sum_c h_v[c][i] * Wv0[c][f]
    int i = o >> 6, f = o & 63;
    float a = 0.0f;
    for (int c = 0; c < F1; c++) a += hv[c * 3 + i] * Wv0[c * F0 + f];
    out[192 + o] = a;
  }
  if (lane < 3) out[384 + lane] = x[(size_t)node * 3 + lane];
  if (lane == 3) out[387] = 0.0f;
}

// ---------------------------------------------------------------------------
// Message + scatter with cooperative radial-row staging.
// Block = (batch, 64-receiver tile, 32-sender chunk); 512 threads = 8 waves
// = 8 feature slices; lane = receiver.
// Per sender-iter: all 512 threads cooperatively load the 64 needed table
// rows (64 x 384B) into an LDS stage (stride 400B -> conflict-free b128),
// then each wave reads its 48B slice per lane. Row indices precomputed in
// a 4KB LDS jtab. Next iter's rows loaded during compute (latency hidden).
// Straight-line, statically-indexed code (R3/R4 spill lessons).
// ---------------------------------------------------------------------------
#define LOADNEXT(ii)                                                      \
  {                                                                       \
    int ja0 = jt[ii][e0], ja1 = jt[ii][e1], ja2 = jt[ii][e2];             \
    c0 = *(const uint4*)(tb + (size_t)ja0 * 384 + bo0);                   \
    c1 = *(const uint4*)(tb + (size_t)ja1 * 384 + bo1);                   \
    c2 = *(const uint4*)(tb + (size_t)ja2 * 384 + bo2);                   \
  }

__launch_bounds__(512, 4)
__global__ void msg_k(const float* __restrict__ nf, const __hip_bfloat16* __restrict__ table_l,
                      const float* __restrict__ x, float* __restrict__ partial) {
  __shared__ float snf[CHUNK][NF];       // 49,664 B
  __shared__ uint32_t stage[6400];       // 25,600 B = 64 rows x 400 B
  __shared__ uint16_t jt[CHUNK][64];     //  4,096 B
  int bid = blockIdx.x;
  int b   = bid / (RTILES * SSPLIT);
  int rem = bid - b * (RTILES * SSPLIT);
  int rt  = rem / SSPLIT;
  int ss  = rem - rt * SSPLIT;
  int tid  = threadIdx.x;
  int w    = tid >> 6;     // feature slice 0..7
  int lane = tid & 63;     // local receiver
  int r    = rt * 64 + lane;

  // stage sender features
  const f32x4* src = (const f32x4*)(nf + (size_t)(b * NN + ss * CHUNK) * NF);
  for (int i = tid; i < CHUNK * NF / 4; i += 512) ((f32x4*)snf)[i] = src[i];

  // precompute all (sender, receiver) table-row indices for this block
#pragma unroll
  for (int m = 0; m < 4; m++) {
    int idx = tid + 512 * m;            // 2048 = CHUNK*64 entries
    int si = idx >> 6, e = idx & 63;
    int s = ss * CHUNK + si, rr = rt * 64 + e;
    const float* ps = x + ((size_t)b * NN + s) * 3;
    const float* pr = x + ((size_t)b * NN + rr) * 3;
    float v0 = pr[0] - ps[0], v1 = pr[1] - ps[1], v2 = pr[2] - ps[2];
    float d = sqrtf(v0 * v0 + v1 * v1 + v2 * v2);
    int j = (int)fminf(d * TSCALE + 0.5f, (float)(TROWS - 1));
    if (s == rr) j = TROWS;             // diagonal -> zero row
    jt[si][e] = (uint16_t)j;
  }

  const float* xp = x + ((size_t)b * NN + r) * 3;
  float xr0 = xp[0], xr1 = xp[1], xr2 = xp[2];

  // chunk map: q = tid + 512k -> row e = q/24, part p = q%24 (16B chunks)
  int q0 = tid, q1 = tid + 512, q2 = tid + 1024;
  int e0 = q0 / 24, p0 = q0 - 24 * e0;
  int e1 = q1 / 24, p1 = q1 - 24 * e1;
  int e2 = q2 / 24, p2 = q2 - 24 * e2;
  int wi0 = 25 * e0 + p0, wi1 = 25 * e1 + p1, wi2 = 25 * e2 + p2;  // uint4 slot
  int bo0 = p0 * 16, bo1 = p1 * 16, bo2 = p2 * 16;
  const char* tb = (const char*)table_l;

  float a0[8];
  float a1[12];
#pragma unroll
  for (int k = 0; k < 8; k++) a0[k] = 0.0f;
#pragma unroll
  for (int k = 0; k < 12; k++) a1[k] = 0.0f;

  __syncthreads();                       // snf + jt ready

  uint4 c0, c1, c2;
  LOADNEXT(0);

  int rb = 25 * lane + 3 * w;            // this thread's slice base (uint4 slot)

  for (int i = 0; i < CHUNK; i++) {
    __syncthreads();                     // stage free (prev compute done)
    ((uint4*)stage)[wi0] = c0;           // waitcnt auto-inserted before ds_write
    ((uint4*)stage)[wi1] = c1;
    ((uint4*)stage)[wi2] = c2;
    __syncthreads();                     // stage ready
    if (i + 1 < CHUNK) LOADNEXT(i + 1);  // issue next rows during compute

    const float* sn = &snf[i][0];
    f32x4 xs = *(const f32x4*)(sn + 384);
    float v0 = xr0 - xs[0], v1 = xr1 - xs[1], v2 = xr2 - xs[2];
    float d2 = v0 * v0 + v1 * v1 + v2 * v2;
    float ri = rsqrtf(d2 + 1e-20f);
    float cu0 = v0 * ri, cu1 = v1 * ri, cu2 = v2 * ri;

    uint4 s0 = ((const uint4*)stage)[rb];
    uint4 s1 = ((const uint4*)stage)[rb + 1];
    uint4 s2 = ((const uint4*)stage)[rb + 2];
    uint32_t dw[12];
    *(uint4*)(dw + 0) = s0; *(uint4*)(dw + 4) = s1; *(uint4*)(dw + 8) = s2;
    float wv[24];   // [w0(8)|w3(8)|w1(4)|w2(4)]
#pragma unroll
    for (int m = 0; m < 12; m++) {
      wv[2 * m]     = __uint_as_float(dw[m] << 16);
      wv[2 * m + 1] = __uint_as_float(dw[m] & 0xffff0000u);
    }

    // a0: w0*hm + w3*(u . hv0)  -- all snf reads are b128 broadcasts
    f32x4 hmA = *(const f32x4*)(sn + w * 8);
    f32x4 hmB = *(const f32x4*)(sn + w * 8 + 4);
    f32x4 p0A = *(const f32x4*)(sn + 192 + w * 8);
    f32x4 p0B = *(const f32x4*)(sn + 192 + w * 8 + 4);
    f32x4 p1A = *(const f32x4*)(sn + 256 + w * 8);
    f32x4 p1B = *(const f32x4*)(sn + 256 + w * 8 + 4);
    f32x4 p2A = *(const f32x4*)(sn + 320 + w * 8);
    f32x4 p2B = *(const f32x4*)(sn + 320 + w * 8 + 4);
#pragma unroll
    for (int k = 0; k < 4; k++) {
      float dvA = cu0 * p0A[k] + cu1 * p1A[k] + cu2 * p2A[k];
      a0[k]     += wv[k] * hmA[k] + wv[8 + k] * dvA;
      float dvB = cu0 * p0B[k] + cu1 * p1B[k] + cu2 * p2B[k];
      a0[4 + k] += wv[4 + k] * hmB[k] + wv[12 + k] * dvB;
    }
    // a1: (w1*hsv + w2*(u.hvv))*u - (w2/3)*hvv
    f32x4 hsv4 = *(const f32x4*)(sn + 64 + w * 4);
    float ga[12];
    *(f32x4*)(ga + 0) = *(const f32x4*)(sn + 96 + w * 12);
    *(f32x4*)(ga + 4) = *(const f32x4*)(sn + 96 + w * 12 + 4);
    *(f32x4*)(ga + 8) = *(const f32x4*)(sn + 96 + w * 12 + 8);
#pragma unroll
    for (int c = 0; c < 4; c++) {
      float g0 = ga[c * 3], g1 = ga[c * 3 + 1], g2 = ga[c * 3 + 2];
      float qd = cu0 * g0 + cu1 * g1 + cu2 * g2;
      float coef = wv[16 + c] * hsv4[c] + wv[20 + c] * qd;
      float t3 = wv[20 + c] * (1.0f / 3.0f);
      a1[c * 3]     += coef * cu0 - t3 * g0;
      a1[c * 3 + 1] += coef * cu1 - t3 * g1;
      a1[c * 3 + 2] += coef * cu2 - t3 * g2;
    }
  }

  float* pw = partial + (size_t)(b * SSPLIT + ss) * ACC * NN;
#pragma unroll
  for (int k = 0; k < 8; k++) pw[(w * 8 + k) * NN + r] = a0[k];
#pragma unroll
  for (int c = 0; c < 4; c++) {
#pragma unroll
    for (int i = 0; i < 3; i++)
      pw[(64 + (w * 4 + c) * 3 + i) * NN + r] = a1[c * 3 + i];
  }
}

// ---------------------------------------------------------------------------
// Reduce partials, polynomial correction, node update (weights pre-offset).
// ---------------------------------------------------------------------------
__global__ void update_k(const float* __restrict__ partial, const float* __restrict__ Wc,
                         const float* __restrict__ Wself,
                         float* __restrict__ h_s, float* __restrict__ h_v) {
  int node = blockIdx.x;
  int b = node >> 9, n = node & 511;
  int lane = threadIdx.x;   // 64
  __shared__ float a0s[F0], a2s[F0], a3s[F0], hss[F0];
  const float invn = 1.0f / (float)NN;
  float a = 0.0f;
  for (int ss = 0; ss < SSPLIT; ss++)
    a += partial[((size_t)(b * SSPLIT + ss) * ACC + lane) * NN + n];
  a *= invn;
  a0s[lane] = a; a2s[lane] = a * a; a3s[lane] = a * a * a;
  hss[lane] = h_s[(size_t)node * F0 + lane];
  for (int o = lane; o < 96; o += 64) {
    float v = 0.0f;
    for (int ss = 0; ss < SSPLIT; ss++)
      v += partial[((size_t)(b * SSPLIT + ss) * ACC + 64 + o) * NN + n];
    h_v[(size_t)node * F1 * 3 + o] += v * invn;
  }
  __syncthreads();
  float val = 0.0f;
  for (int f = 0; f < F0; f++) {
    val += hss[f] * Wself[f * F0 + lane];
    val += a0s[f] * Wc[(0 * F0 + f) * F0 + lane];
    val += a2s[f] * Wc[(1 * F0 + f) * F0 + lane];
    val += a3s[f] * Wc[(2 * F0 + f) * F0 + lane];
  }
  h_s[(size_t)node * F0 + lane] = val;
}

// Output head: vecf = h_v @ Woutv (first), inv = silu(h_s)@Wouts@Wfin + bfin.
__global__ void out_k(const float* __restrict__ h_s, const float* __restrict__ h_v,
                      const float* __restrict__ Wouts, const float* __restrict__ Wfin,
                      const float* __restrict__ bfin, const float* __restrict__ Woutv,
                      float* __restrict__ out) {
  int node = blockIdx.x;
  int lane = threadIdx.x;   // 64
  __shared__ float t[F0], g[NINVD];
  float h = h_s[(size_t)node * F0 + lane];
  t[lane] = h / (1.0f + __expf(-h));
  __syncthreads();
  float a = 0.0f;
  for (int f = 0; f < F0; f++) a += t[f] * Wouts[f * NINVD + lane];
  g[lane] = a;
  __syncthreads();
  float v = bfin[lane];
  for (int k = 0; k < NINVD; k++) v += g[k] * Wfin[k * NINVD + lane];
  out[INV_OFF + (size_t)node * NINVD + lane] = v;
  if (lane < NVECD * 3) {
    int gg = lane / 3, i = lane - gg * 3;
    float s = 0.0f;
    for (int f = 0; f < F1; f++) s += h_v[(size_t)node * F1 * 3 + f * 3 + i] * Woutv[f * NVECD + gg];
    out[(size_t)node * (NVECD * 3) + lane] = s;
  }
}

extern "C" void kernel_launch(void* const* d_in, const int* in_sizes, int n_in,
                              void* d_out, int out_size, void* d_ws, size_t ws_size,
                              hipStream_t stream) {
  const float* x     = (const float*)d_in[0];
  // d_in[1] senders, d_in[2] receivers: dense-graph structure is known, unused.
  const float* embed = (const float*)d_in[3];
  const float* Wr1   = (const float*)d_in[4];
  const float* Wr2   = (const float*)d_in[5];
  const float* Wm    = (const float*)d_in[6];
  const float* Wc    = (const float*)d_in[7];
  const float* Wself = (const float*)d_in[8];
  const float* Wsv   = (const float*)d_in[9];
  const float* Wvv   = (const float*)d_in[10];
  const float* Wv0   = (const float*)d_in[11];
  const float* Wouts = (const float*)d_in[12];
  const float* Woutv = (const float*)d_in[13];
  const float* Wfin  = (const float*)d_in[14];
  const float* bfin  = (const float*)d_in[15];
  float* out = (float*)d_out;

  char* ws = (char*)d_ws;
  size_t off = 0;
  auto wsalloc = [&](size_t bytes) {
    void* p = ws + off;
    off += (bytes + 255) & ~(size_t)255;
    return p;
  };
  __hip_bfloat16* table = (__hip_bfloat16*)wsalloc((size_t)LNUM * (TROWS + 1) * RWN * 2);
  float* h_s     = (float*)wsalloc((size_t)BB * NN * F0 * 4);
  float* h_v     = (float*)wsalloc((size_t)BB * NN * F1 * 3 * 4);
  float* nf      = (float*)wsalloc((size_t)BB * NN * NF * 4);
  float* partial = (float*)wsalloc((size_t)BB * SSPLIT * ACC * NN * 4);
  // total workspace: ~27 MB

  table_k<<<LNUM * (TROWS + 1), 192, 0, stream>>>(Wr1, Wr2, table);
  init_k<<<(BB * NN * F1 * 3 + 255) / 256, 256, 0, stream>>>(embed, h_s, h_v);
  for (int l = 0; l < LNUM; l++) {
    nodeprep_k<<<BB * NN, 64, 0, stream>>>(h_s, h_v, x,
                                           Wm + l * F0 * F0, Wsv + l * F0 * F1,
                                           Wvv + l * F1 * F1, Wv0 + l * F1 * F0, nf);
    msg_k<<<BB * RTILES * SSPLIT, 512, 0, stream>>>(nf, table + (size_t)l * (TROWS + 1) * RWN,
                                                    x, partial);
    update_k<<<BB * NN, 64, 0, stream>>>(partial, Wc + l * 3 * F0 * F0,
                                         Wself + l * F0 * F0, h_s, h_v);
  }
  out_k<<<BB * NN, 64, 0, stream>>>(h_s, h_v, Wouts, Wfin, bfin, Woutv, out);
}